// Round 1
// baseline (762.189 us; speedup 1.0000x reference)
//
#include <hip/hip_runtime.h>

#define N_NODES 200000
#define N_EDGES 12800000

__global__ __launch_bounds__(256) void bias_init_kernel(
    const float* __restrict__ Param_b,
    const int* __restrict__ node_label,
    float* __restrict__ y,
    int n_nodes)
{
    int i = blockIdx.x * blockDim.x + threadIdx.x;
    if (i < n_nodes) {
        y[i] = Param_b[node_label[i]];
    }
}

__global__ __launch_bounds__(256) void edge_scatter_kernel(
    const float* __restrict__ x,
    const float* __restrict__ Param_W,
    const int* __restrict__ src,
    const int* __restrict__ dst,
    const int* __restrict__ widx,
    float* __restrict__ y,
    int n_edges)
{
    int i = (blockIdx.x * blockDim.x + threadIdx.x) * 4;
    if (i + 3 < n_edges) {
        // 16B coalesced loads of the three edge-index streams
        int4 s = *reinterpret_cast<const int4*>(src + i);
        int4 d = *reinterpret_cast<const int4*>(dst + i);
        int4 w = *reinterpret_cast<const int4*>(widx + i);

        float m0 = Param_W[w.x] * x[s.x];
        float m1 = Param_W[w.y] * x[s.y];
        float m2 = Param_W[w.z] * x[s.z];
        float m3 = Param_W[w.w] * x[s.w];

        unsafeAtomicAdd(&y[d.x], m0);
        unsafeAtomicAdd(&y[d.y], m1);
        unsafeAtomicAdd(&y[d.z], m2);
        unsafeAtomicAdd(&y[d.w], m3);
    } else {
        for (; i < n_edges; ++i) {
            unsafeAtomicAdd(&y[dst[i]], Param_W[widx[i]] * x[src[i]]);
        }
    }
}

extern "C" void kernel_launch(void* const* d_in, const int* in_sizes, int n_in,
                              void* d_out, int out_size, void* d_ws, size_t ws_size,
                              hipStream_t stream)
{
    const float* x          = (const float*)d_in[0];
    const float* Param_W    = (const float*)d_in[1];
    const float* Param_b    = (const float*)d_in[2];
    const int*   src        = (const int*)d_in[3];
    const int*   dst        = (const int*)d_in[4];
    const int*   weight_idx = (const int*)d_in[5];
    const int*   node_label = (const int*)d_in[6];
    float* y = (float*)d_out;

    int n_nodes = in_sizes[0];
    int n_edges = in_sizes[3];

    // 1) y[i] = Param_b[node_label[i]]  (also initializes the poisoned d_out)
    int init_blocks = (n_nodes + 255) / 256;
    bias_init_kernel<<<init_blocks, 256, 0, stream>>>(Param_b, node_label, y, n_nodes);

    // 2) scatter-add messages: 4 edges per thread
    int n_threads = (n_edges + 3) / 4;
    int blocks = (n_threads + 255) / 256;
    edge_scatter_kernel<<<blocks, 256, 0, stream>>>(x, Param_W, src, dst, weight_idx, y, n_edges);
}

// Round 2
// 444.566 us; speedup vs baseline: 1.7145x; 1.7145x over previous
//
#include <hip/hip_runtime.h>

#define PARTS 13
#define NPP   15388            // nodes per partition (mult of 4); 13*15388 = 200044 >= 200000
#define NCHUNKS 39             // edge chunks; 13*39 = 507 blocks co-resident (2/CU, 61.5KB LDS each)
#define TPB_SCAN 512

// ---------------- Phase A: msg[e] = W[widx[e]] * x[src[e]] ----------------
__global__ __launch_bounds__(256) void msg_kernel(
    const float* __restrict__ x, const float* __restrict__ W,
    const int* __restrict__ src, const int* __restrict__ widx,
    float* __restrict__ msg, int E)
{
    int i = (blockIdx.x * 256 + threadIdx.x) * 4;
    if (i + 3 < E) {
        int4 s = *reinterpret_cast<const int4*>(src + i);
        int4 w = *reinterpret_cast<const int4*>(widx + i);
        float4 m;
        m.x = W[w.x] * x[s.x];
        m.y = W[w.y] * x[s.y];
        m.z = W[w.z] * x[s.z];
        m.w = W[w.w] * x[s.w];
        *reinterpret_cast<float4*>(msg + i) = m;
    } else {
        for (; i < E; ++i) msg[i] = W[widx[i]] * x[src[i]];
    }
}

// ---------------- Phase B: partitioned LDS accumulation ----------------
// block (p, b): scan edge chunk b, accumulate dsts in partition p into LDS,
// flush (non-atomic) to partials[b][p*NPP ..]
__global__ __launch_bounds__(TPB_SCAN, 4) void scan_kernel(
    const int* __restrict__ dst, const float* __restrict__ msg,
    float* __restrict__ partials, int E, int chunk)
{
    __shared__ float acc[NPP];
    int b = blockIdx.x % NCHUNKS;
    int p = blockIdx.x / NCHUNKS;

    for (int i = threadIdx.x; i < NPP; i += TPB_SCAN) acc[i] = 0.0f;
    __syncthreads();

    int lo = b * chunk;              // chunk is a multiple of 4
    int hi = min(E, lo + chunk);     // E is a multiple of 4
    int base = p * NPP;

    const int4*   d4 = reinterpret_cast<const int4*>(dst);
    const float4* m4 = reinterpret_cast<const float4*>(msg);
    for (int g = lo / 4 + threadIdx.x; g < hi / 4; g += TPB_SCAN) {
        int4   d = d4[g];
        float4 m = m4[g];
        unsigned r;
        r = (unsigned)(d.x - base); if (r < NPP) atomicAdd(&acc[r], m.x);
        r = (unsigned)(d.y - base); if (r < NPP) atomicAdd(&acc[r], m.y);
        r = (unsigned)(d.z - base); if (r < NPP) atomicAdd(&acc[r], m.z);
        r = (unsigned)(d.w - base); if (r < NPP) atomicAdd(&acc[r], m.w);
    }
    __syncthreads();

    float* out = partials + (size_t)b * (PARTS * NPP) + base;
    for (int i = threadIdx.x; i < NPP; i += TPB_SCAN) out[i] = acc[i];
}

// ---------------- Phase C: reduce partials + bias ----------------
__global__ __launch_bounds__(256) void reduce_kernel(
    const float* __restrict__ partials, const float* __restrict__ bias,
    const int* __restrict__ label, float* __restrict__ y, int n)
{
    int i = blockIdx.x * 256 + threadIdx.x;
    if (i >= n) return;
    float s = bias[label[i]];
    #pragma unroll 1
    for (int b = 0; b < NCHUNKS; ++b)
        s += partials[(size_t)b * (PARTS * NPP) + i];
    y[i] = s;
}

// ---------------- Fallback (round-1 path) if ws is too small ----------------
__global__ __launch_bounds__(256) void bias_init_kernel(
    const float* __restrict__ Param_b, const int* __restrict__ node_label,
    float* __restrict__ y, int n_nodes)
{
    int i = blockIdx.x * blockDim.x + threadIdx.x;
    if (i < n_nodes) y[i] = Param_b[node_label[i]];
}

__global__ __launch_bounds__(256) void edge_scatter_kernel(
    const float* __restrict__ x, const float* __restrict__ Param_W,
    const int* __restrict__ src, const int* __restrict__ dst,
    const int* __restrict__ widx, float* __restrict__ y, int n_edges)
{
    int i = (blockIdx.x * blockDim.x + threadIdx.x) * 4;
    if (i + 3 < n_edges) {
        int4 s = *reinterpret_cast<const int4*>(src + i);
        int4 d = *reinterpret_cast<const int4*>(dst + i);
        int4 w = *reinterpret_cast<const int4*>(widx + i);
        unsafeAtomicAdd(&y[d.x], Param_W[w.x] * x[s.x]);
        unsafeAtomicAdd(&y[d.y], Param_W[w.y] * x[s.y]);
        unsafeAtomicAdd(&y[d.z], Param_W[w.z] * x[s.z]);
        unsafeAtomicAdd(&y[d.w], Param_W[w.w] * x[s.w]);
    } else {
        for (; i < n_edges; ++i)
            unsafeAtomicAdd(&y[dst[i]], Param_W[widx[i]] * x[src[i]]);
    }
}

extern "C" void kernel_launch(void* const* d_in, const int* in_sizes, int n_in,
                              void* d_out, int out_size, void* d_ws, size_t ws_size,
                              hipStream_t stream)
{
    const float* x          = (const float*)d_in[0];
    const float* Param_W    = (const float*)d_in[1];
    const float* Param_b    = (const float*)d_in[2];
    const int*   src        = (const int*)d_in[3];
    const int*   dst        = (const int*)d_in[4];
    const int*   weight_idx = (const int*)d_in[5];
    const int*   node_label = (const int*)d_in[6];
    float* y = (float*)d_out;

    int n_nodes = in_sizes[0];
    int E       = in_sizes[3];

    size_t msg_elems      = (size_t)E;
    size_t partials_elems = (size_t)NCHUNKS * PARTS * NPP;
    size_t need_bytes     = (msg_elems + partials_elems) * sizeof(float);

    if (ws_size >= need_bytes) {
        float* msg      = (float*)d_ws;
        float* partials = msg + msg_elems;

        // Phase A
        int tA = (E + 3) / 4;
        msg_kernel<<<(tA + 255) / 256, 256, 0, stream>>>(x, Param_W, src, weight_idx, msg, E);

        // Phase B
        int chunk = (((E + NCHUNKS - 1) / NCHUNKS) + 3) & ~3;  // mult of 4
        scan_kernel<<<PARTS * NCHUNKS, TPB_SCAN, 0, stream>>>(dst, msg, partials, E, chunk);

        // Phase C
        reduce_kernel<<<(n_nodes + 255) / 256, 256, 0, stream>>>(
            partials, Param_b, node_label, y, n_nodes);
    } else {
        // Fallback: direct atomic path (round-1)
        bias_init_kernel<<<(n_nodes + 255) / 256, 256, 0, stream>>>(
            Param_b, node_label, y, n_nodes);
        int t = (E + 3) / 4;
        edge_scatter_kernel<<<(t + 255) / 256, 256, 0, stream>>>(
            x, Param_W, src, dst, weight_idx, y, E);
    }
}

// Round 3
// 419.345 us; speedup vs baseline: 1.8176x; 1.0601x over previous
//
#include <hip/hip_runtime.h>

// ---------------- New path constants ----------------
#define PARTS 13
#define NPP_SHIFT 14
#define NPP 16384                 // nodes per partition (power of 2)
#define PADDED_N (PARTS * NPP)    // 212992 >= 200000
#define CAP 1150000               // pairs capacity per partition (mean ~1.049M, ~100 sigma margin)
#define NC 39                     // scan chunks per partition -> 13*39=507 blocks (2/CU)
#define TILE 4096
#define TPB_BIN 256
#define TPB_SCAN 512

__global__ void zero_counts_kernel(int* __restrict__ gcount) {
    if (threadIdx.x < PARTS) gcount[threadIdx.x] = 0;
}

// One pass: read edges, compute m = W[widx]*x[src], radix-partition by dst>>14
// into per-partition contiguous pair buffers.
__global__ __launch_bounds__(TPB_BIN, 4) void bin_kernel(
    const float* __restrict__ x, const float* __restrict__ W,
    const int* __restrict__ src, const int* __restrict__ widx,
    const int* __restrict__ dst,
    uint2* __restrict__ pairs, int* __restrict__ gcount, int E)
{
    __shared__ uint2 tile[TILE];
    __shared__ int hist[PARTS];
    __shared__ int cursor[PARTS];

    int t = threadIdx.x;
    long tile_base = (long)blockIdx.x * TILE;
    int tile_n = (int)min((long)TILE, (long)E - tile_base);  // multiple of 4 (E%4==0)

    if (t < PARTS) hist[t] = 0;
    __syncthreads();

    // pass 1: coalesced int4 loads, compute, stage in LDS, histogram
    #pragma unroll
    for (int k = 0; k < TILE / (4 * TPB_BIN); ++k) {
        int g = k * TPB_BIN + t;       // int4-group index within tile
        int i0 = g * 4;
        if (i0 < tile_n) {
            long gi = tile_base + i0;
            int4 s = *reinterpret_cast<const int4*>(src + gi);
            int4 w = *reinterpret_cast<const int4*>(widx + gi);
            int4 d = *reinterpret_cast<const int4*>(dst + gi);
            float m0 = W[w.x] * x[s.x];
            float m1 = W[w.y] * x[s.y];
            float m2 = W[w.z] * x[s.z];
            float m3 = W[w.w] * x[s.w];
            int p0 = d.x >> NPP_SHIFT, p1 = d.y >> NPP_SHIFT;
            int p2 = d.z >> NPP_SHIFT, p3 = d.w >> NPP_SHIFT;
            tile[i0 + 0] = make_uint2((unsigned)((p0 << 16) | (d.x & (NPP - 1))), __float_as_uint(m0));
            tile[i0 + 1] = make_uint2((unsigned)((p1 << 16) | (d.y & (NPP - 1))), __float_as_uint(m1));
            tile[i0 + 2] = make_uint2((unsigned)((p2 << 16) | (d.z & (NPP - 1))), __float_as_uint(m2));
            tile[i0 + 3] = make_uint2((unsigned)((p3 << 16) | (d.w & (NPP - 1))), __float_as_uint(m3));
            atomicAdd(&hist[p0], 1);
            atomicAdd(&hist[p1], 1);
            atomicAdd(&hist[p2], 1);
            atomicAdd(&hist[p3], 1);
        }
    }
    __syncthreads();

    // reserve contiguous slots per partition: 13 global atomics per block
    if (t < PARTS) cursor[t] = atomicAdd(&gcount[t], hist[t]);
    __syncthreads();

    // pass 2: scatter tile into per-partition regions
    for (int i = t; i < tile_n; i += TPB_BIN) {
        uint2 pr = tile[i];
        int p = (int)(pr.x >> 16);
        int slot = atomicAdd(&cursor[p], 1);
        if (slot < CAP)
            pairs[(size_t)p * CAP + slot] = pr;
    }
}

// Each block (p,c): accumulate a slice of partition p's pairs into 64KB LDS, flush.
__global__ __launch_bounds__(TPB_SCAN, 2) void scan2_kernel(
    const uint2* __restrict__ pairs, const int* __restrict__ gcount,
    float* __restrict__ partials)
{
    __shared__ float acc[NPP];
    int c = blockIdx.x % NC;
    int p = blockIdx.x / NC;

    for (int i = threadIdx.x; i < NPP; i += TPB_SCAN) acc[i] = 0.0f;
    __syncthreads();

    int cnt = min(gcount[p], CAP);
    int lo = (int)((long)c * cnt / NC);
    int hi = (int)((long)(c + 1) * cnt / NC);
    const uint2* base = pairs + (size_t)p * CAP;
    for (int i = lo + threadIdx.x; i < hi; i += TPB_SCAN) {
        uint2 pr = base[i];
        atomicAdd(&acc[pr.x & (NPP - 1)], __uint_as_float(pr.y));
    }
    __syncthreads();

    float* out = partials + (size_t)c * PADDED_N + p * NPP;
    for (int i = threadIdx.x; i < NPP; i += TPB_SCAN) out[i] = acc[i];
}

__global__ __launch_bounds__(256) void reduce2_kernel(
    const float* __restrict__ partials, const float* __restrict__ bias,
    const int* __restrict__ label, float* __restrict__ y, int n)
{
    int i = blockIdx.x * 256 + threadIdx.x;
    if (i >= n) return;
    float s = bias[label[i]];
    #pragma unroll 1
    for (int c = 0; c < NC; ++c)
        s += partials[(size_t)c * PADDED_N + i];
    y[i] = s;
}

// ---------------- Fallback path A (round-2: broadcast partitions) ----------------
#define F_PARTS 13
#define F_NPP 15388
#define F_NCHUNKS 39
#define F_TPB 512

__global__ __launch_bounds__(256) void msg_kernel(
    const float* __restrict__ x, const float* __restrict__ W,
    const int* __restrict__ src, const int* __restrict__ widx,
    float* __restrict__ msg, int E)
{
    int i = (blockIdx.x * 256 + threadIdx.x) * 4;
    if (i + 3 < E) {
        int4 s = *reinterpret_cast<const int4*>(src + i);
        int4 w = *reinterpret_cast<const int4*>(widx + i);
        float4 m;
        m.x = W[w.x] * x[s.x];
        m.y = W[w.y] * x[s.y];
        m.z = W[w.z] * x[s.z];
        m.w = W[w.w] * x[s.w];
        *reinterpret_cast<float4*>(msg + i) = m;
    } else {
        for (; i < E; ++i) msg[i] = W[widx[i]] * x[src[i]];
    }
}

__global__ __launch_bounds__(F_TPB, 4) void scan_kernel(
    const int* __restrict__ dst, const float* __restrict__ msg,
    float* __restrict__ partials, int E, int chunk)
{
    __shared__ float acc[F_NPP];
    int b = blockIdx.x % F_NCHUNKS;
    int p = blockIdx.x / F_NCHUNKS;
    for (int i = threadIdx.x; i < F_NPP; i += F_TPB) acc[i] = 0.0f;
    __syncthreads();
    int lo = b * chunk;
    int hi = min(E, lo + chunk);
    int base = p * F_NPP;
    const int4*   d4 = reinterpret_cast<const int4*>(dst);
    const float4* m4 = reinterpret_cast<const float4*>(msg);
    for (int g = lo / 4 + threadIdx.x; g < hi / 4; g += F_TPB) {
        int4 d = d4[g];
        float4 m = m4[g];
        unsigned r;
        r = (unsigned)(d.x - base); if (r < F_NPP) atomicAdd(&acc[r], m.x);
        r = (unsigned)(d.y - base); if (r < F_NPP) atomicAdd(&acc[r], m.y);
        r = (unsigned)(d.z - base); if (r < F_NPP) atomicAdd(&acc[r], m.z);
        r = (unsigned)(d.w - base); if (r < F_NPP) atomicAdd(&acc[r], m.w);
    }
    __syncthreads();
    float* out = partials + (size_t)b * (F_PARTS * F_NPP) + base;
    for (int i = threadIdx.x; i < F_NPP; i += F_TPB) out[i] = acc[i];
}

__global__ __launch_bounds__(256) void freduce_kernel(
    const float* __restrict__ partials, const float* __restrict__ bias,
    const int* __restrict__ label, float* __restrict__ y, int n)
{
    int i = blockIdx.x * 256 + threadIdx.x;
    if (i >= n) return;
    float s = bias[label[i]];
    #pragma unroll 1
    for (int b = 0; b < F_NCHUNKS; ++b)
        s += partials[(size_t)b * (F_PARTS * F_NPP) + i];
    y[i] = s;
}

// ---------------- Fallback path B (round-1: direct atomics) ----------------
__global__ __launch_bounds__(256) void bias_init_kernel(
    const float* __restrict__ Param_b, const int* __restrict__ node_label,
    float* __restrict__ y, int n_nodes)
{
    int i = blockIdx.x * blockDim.x + threadIdx.x;
    if (i < n_nodes) y[i] = Param_b[node_label[i]];
}

__global__ __launch_bounds__(256) void edge_scatter_kernel(
    const float* __restrict__ x, const float* __restrict__ Param_W,
    const int* __restrict__ src, const int* __restrict__ dst,
    const int* __restrict__ widx, float* __restrict__ y, int n_edges)
{
    int i = (blockIdx.x * blockDim.x + threadIdx.x) * 4;
    if (i + 3 < n_edges) {
        int4 s = *reinterpret_cast<const int4*>(src + i);
        int4 d = *reinterpret_cast<const int4*>(dst + i);
        int4 w = *reinterpret_cast<const int4*>(widx + i);
        unsafeAtomicAdd(&y[d.x], Param_W[w.x] * x[s.x]);
        unsafeAtomicAdd(&y[d.y], Param_W[w.y] * x[s.y]);
        unsafeAtomicAdd(&y[d.z], Param_W[w.z] * x[s.z]);
        unsafeAtomicAdd(&y[d.w], Param_W[w.w] * x[s.w]);
    } else {
        for (; i < n_edges; ++i)
            unsafeAtomicAdd(&y[dst[i]], Param_W[widx[i]] * x[src[i]]);
    }
}

extern "C" void kernel_launch(void* const* d_in, const int* in_sizes, int n_in,
                              void* d_out, int out_size, void* d_ws, size_t ws_size,
                              hipStream_t stream)
{
    const float* x          = (const float*)d_in[0];
    const float* Param_W    = (const float*)d_in[1];
    const float* Param_b    = (const float*)d_in[2];
    const int*   src        = (const int*)d_in[3];
    const int*   dst        = (const int*)d_in[4];
    const int*   weight_idx = (const int*)d_in[5];
    const int*   node_label = (const int*)d_in[6];
    float* y = (float*)d_out;

    int n_nodes = in_sizes[0];
    int E       = in_sizes[3];

    // New-path workspace: [gcount pad 256B][pairs 13*CAP uint2][partials NC*PADDED_N f32]
    size_t pairs_bytes    = (size_t)PARTS * CAP * sizeof(uint2);     // ~119.6 MB
    size_t partials_bytes = (size_t)NC * PADDED_N * sizeof(float);   // ~33.2 MB
    size_t need_new = 256 + pairs_bytes + partials_bytes;

    size_t fa_msg      = (size_t)E;
    size_t fa_partials = (size_t)F_NCHUNKS * F_PARTS * F_NPP;
    size_t need_fa     = (fa_msg + fa_partials) * sizeof(float);     // ~82.4 MB

    if (ws_size >= need_new) {
        int*   gcount   = (int*)d_ws;
        uint2* pairs    = (uint2*)((char*)d_ws + 256);
        float* partials = (float*)((char*)d_ws + 256 + pairs_bytes);

        zero_counts_kernel<<<1, 64, 0, stream>>>(gcount);

        int bin_blocks = (E + TILE - 1) / TILE;
        bin_kernel<<<bin_blocks, TPB_BIN, 0, stream>>>(
            x, Param_W, src, weight_idx, dst, pairs, gcount, E);

        scan2_kernel<<<PARTS * NC, TPB_SCAN, 0, stream>>>(pairs, gcount, partials);

        reduce2_kernel<<<(n_nodes + 255) / 256, 256, 0, stream>>>(
            partials, Param_b, node_label, y, n_nodes);
    } else if (ws_size >= need_fa) {
        float* msg      = (float*)d_ws;
        float* partials = msg + fa_msg;
        int tA = (E + 3) / 4;
        msg_kernel<<<(tA + 255) / 256, 256, 0, stream>>>(x, Param_W, src, weight_idx, msg, E);
        int chunk = (((E + F_NCHUNKS - 1) / F_NCHUNKS) + 3) & ~3;
        scan_kernel<<<F_PARTS * F_NCHUNKS, F_TPB, 0, stream>>>(dst, msg, partials, E, chunk);
        freduce_kernel<<<(n_nodes + 255) / 256, 256, 0, stream>>>(
            partials, Param_b, node_label, y, n_nodes);
    } else {
        bias_init_kernel<<<(n_nodes + 255) / 256, 256, 0, stream>>>(
            Param_b, node_label, y, n_nodes);
        int t = (E + 3) / 4;
        edge_scatter_kernel<<<(t + 255) / 256, 256, 0, stream>>>(
            x, Param_W, src, dst, weight_idx, y, E);
    }
}

// Round 4
// 410.582 us; speedup vs baseline: 1.8564x; 1.0213x over previous
//
#include <hip/hip_runtime.h>

// ---------------- Constants ----------------
#define PARTS 13
#define NPP_SHIFT 14
#define NPP 16384                 // nodes per partition (power of 2)
#define PADDED_N (PARTS * NPP)    // 212992 >= 200000
#define CAP 1150000               // pairs capacity per partition
#define NC 39                     // scan chunks per partition -> 13*39=507 blocks
#define TILE 4096
#define TPB_BIN 256
#define EPT 16                    // edges per thread in bin (TILE/TPB_BIN)
#define TPB_SCAN 512

__global__ void zero_counts_kernel(int* __restrict__ gcount) {
    if (threadIdx.x < PARTS) gcount[threadIdx.x] = 0;
}

// One pass: read edges, compute m = W[widx]*x[src], counting-sort the tile by
// partition in LDS, then write coalesced contiguous runs per partition.
__global__ __launch_bounds__(TPB_BIN, 4) void bin_kernel(
    const float* __restrict__ x, const float* __restrict__ W,
    const int* __restrict__ src, const int* __restrict__ widx,
    const int* __restrict__ dst,
    uint2* __restrict__ pairs, int* __restrict__ gcount, int E)
{
    __shared__ uint2 sorted[TILE];
    __shared__ int hist[PARTS];
    __shared__ int start[PARTS + 1];
    __shared__ int gbase[PARTS];

    int t = threadIdx.x;
    long tile_base = (long)blockIdx.x * TILE;
    int tile_n = (int)min((long)TILE, (long)E - tile_base);

    if (t < PARTS) hist[t] = 0;
    __syncthreads();

    // phase 1: load + compute + rank (stable within partition via LDS atomic)
    unsigned keyr[EPT];   // p<<28 | rank<<14 | local   (rank<4096, local<16384, p<13)
    float    valr[EPT];
    #pragma unroll
    for (int k = 0; k < EPT / 4; ++k) {
        int g = k * TPB_BIN + t;       // int4-group index within tile
        int i0 = g * 4;
        if (i0 < tile_n) {
            long gi = tile_base + i0;
            int4 s = *reinterpret_cast<const int4*>(src + gi);
            int4 w = *reinterpret_cast<const int4*>(widx + gi);
            int4 d = *reinterpret_cast<const int4*>(dst + gi);
            float m0 = W[w.x] * x[s.x];
            float m1 = W[w.y] * x[s.y];
            float m2 = W[w.z] * x[s.z];
            float m3 = W[w.w] * x[s.w];
            int p0 = d.x >> NPP_SHIFT, p1 = d.y >> NPP_SHIFT;
            int p2 = d.z >> NPP_SHIFT, p3 = d.w >> NPP_SHIFT;
            int r0 = atomicAdd(&hist[p0], 1);
            int r1 = atomicAdd(&hist[p1], 1);
            int r2 = atomicAdd(&hist[p2], 1);
            int r3 = atomicAdd(&hist[p3], 1);
            keyr[k*4+0] = ((unsigned)p0 << 28) | ((unsigned)r0 << 14) | (unsigned)(d.x & (NPP-1));
            keyr[k*4+1] = ((unsigned)p1 << 28) | ((unsigned)r1 << 14) | (unsigned)(d.y & (NPP-1));
            keyr[k*4+2] = ((unsigned)p2 << 28) | ((unsigned)r2 << 14) | (unsigned)(d.z & (NPP-1));
            keyr[k*4+3] = ((unsigned)p3 << 28) | ((unsigned)r3 << 14) | (unsigned)(d.w & (NPP-1));
            valr[k*4+0] = m0; valr[k*4+1] = m1; valr[k*4+2] = m2; valr[k*4+3] = m3;
        } else {
            keyr[k*4+0] = 0xFFFFFFFFu; keyr[k*4+1] = 0xFFFFFFFFu;
            keyr[k*4+2] = 0xFFFFFFFFu; keyr[k*4+3] = 0xFFFFFFFFu;
        }
    }
    __syncthreads();

    // phase 2: exclusive scan of hist (13 entries) + global slot reservation
    if (t == 0) {
        int acc = 0;
        for (int p = 0; p < PARTS; ++p) { start[p] = acc; acc += hist[p]; }
        start[PARTS] = acc;
    }
    __syncthreads();
    if (t < PARTS) gbase[t] = atomicAdd(&gcount[t], hist[t]);
    __syncthreads();

    // phase 3: scatter into partition-sorted LDS tile
    #pragma unroll
    for (int k = 0; k < EPT; ++k) {
        unsigned key = keyr[k];
        if (key != 0xFFFFFFFFu) {
            int p    = (int)(key >> 28);
            int rank = (int)((key >> 14) & 0x3FFFu);
            int loc  = (int)(key & 0x3FFFu);
            sorted[start[p] + rank] = make_uint2(((unsigned)p << 16) | (unsigned)loc,
                                                 __float_as_uint(valr[k]));
        }
    }
    __syncthreads();

    // phase 4: coalesced write-out of contiguous partition runs
    for (int i = t; i < tile_n; i += TPB_BIN) {
        uint2 pr = sorted[i];
        int p = (int)(pr.x >> 16);
        int idx = gbase[p] + (i - start[p]);
        if (idx < CAP)
            pairs[(size_t)p * CAP + idx] = pr;
    }
}

// Each block (p,c): accumulate a slice of partition p's pairs into 64KB LDS, flush.
__global__ __launch_bounds__(TPB_SCAN, 2) void scan2_kernel(
    const uint2* __restrict__ pairs, const int* __restrict__ gcount,
    float* __restrict__ partials)
{
    __shared__ float acc[NPP];
    int c = blockIdx.x % NC;
    int p = blockIdx.x / NC;

    for (int i = threadIdx.x; i < NPP; i += TPB_SCAN) acc[i] = 0.0f;
    __syncthreads();

    int cnt = min(gcount[p], CAP);
    int lo = (int)((long)c * cnt / NC);
    int hi = (int)((long)(c + 1) * cnt / NC);
    const uint2* base = pairs + (size_t)p * CAP;
    for (int i = lo + threadIdx.x; i < hi; i += TPB_SCAN) {
        uint2 pr = base[i];
        atomicAdd(&acc[pr.x & (NPP - 1)], __uint_as_float(pr.y));
    }
    __syncthreads();

    float* out = partials + (size_t)c * PADDED_N + p * NPP;
    for (int i = threadIdx.x; i < NPP; i += TPB_SCAN) out[i] = acc[i];
}

__global__ __launch_bounds__(256) void reduce2_kernel(
    const float* __restrict__ partials, const float* __restrict__ bias,
    const int* __restrict__ label, float* __restrict__ y, int n)
{
    int i = blockIdx.x * 256 + threadIdx.x;
    if (i >= n) return;
    float s = bias[label[i]];
    #pragma unroll 1
    for (int c = 0; c < NC; ++c)
        s += partials[(size_t)c * PADDED_N + i];
    y[i] = s;
}

// ---------------- Fallback path A (round-2: broadcast partitions) ----------------
#define F_PARTS 13
#define F_NPP 15388
#define F_NCHUNKS 39
#define F_TPB 512

__global__ __launch_bounds__(256) void msg_kernel(
    const float* __restrict__ x, const float* __restrict__ W,
    const int* __restrict__ src, const int* __restrict__ widx,
    float* __restrict__ msg, int E)
{
    int i = (blockIdx.x * 256 + threadIdx.x) * 4;
    if (i + 3 < E) {
        int4 s = *reinterpret_cast<const int4*>(src + i);
        int4 w = *reinterpret_cast<const int4*>(widx + i);
        float4 m;
        m.x = W[w.x] * x[s.x];
        m.y = W[w.y] * x[s.y];
        m.z = W[w.z] * x[s.z];
        m.w = W[w.w] * x[s.w];
        *reinterpret_cast<float4*>(msg + i) = m;
    } else {
        for (; i < E; ++i) msg[i] = W[widx[i]] * x[src[i]];
    }
}

__global__ __launch_bounds__(F_TPB, 4) void scan_kernel(
    const int* __restrict__ dst, const float* __restrict__ msg,
    float* __restrict__ partials, int E, int chunk)
{
    __shared__ float acc[F_NPP];
    int b = blockIdx.x % F_NCHUNKS;
    int p = blockIdx.x / F_NCHUNKS;
    for (int i = threadIdx.x; i < F_NPP; i += F_TPB) acc[i] = 0.0f;
    __syncthreads();
    int lo = b * chunk;
    int hi = min(E, lo + chunk);
    int base = p * F_NPP;
    const int4*   d4 = reinterpret_cast<const int4*>(dst);
    const float4* m4 = reinterpret_cast<const float4*>(msg);
    for (int g = lo / 4 + threadIdx.x; g < hi / 4; g += F_TPB) {
        int4 d = d4[g];
        float4 m = m4[g];
        unsigned r;
        r = (unsigned)(d.x - base); if (r < F_NPP) atomicAdd(&acc[r], m.x);
        r = (unsigned)(d.y - base); if (r < F_NPP) atomicAdd(&acc[r], m.y);
        r = (unsigned)(d.z - base); if (r < F_NPP) atomicAdd(&acc[r], m.z);
        r = (unsigned)(d.w - base); if (r < F_NPP) atomicAdd(&acc[r], m.w);
    }
    __syncthreads();
    float* out = partials + (size_t)b * (F_PARTS * F_NPP) + base;
    for (int i = threadIdx.x; i < F_NPP; i += F_TPB) out[i] = acc[i];
}

__global__ __launch_bounds__(256) void freduce_kernel(
    const float* __restrict__ partials, const float* __restrict__ bias,
    const int* __restrict__ label, float* __restrict__ y, int n)
{
    int i = blockIdx.x * 256 + threadIdx.x;
    if (i >= n) return;
    float s = bias[label[i]];
    #pragma unroll 1
    for (int b = 0; b < F_NCHUNKS; ++b)
        s += partials[(size_t)b * (F_PARTS * F_NPP) + i];
    y[i] = s;
}

// ---------------- Fallback path B (round-1: direct atomics) ----------------
__global__ __launch_bounds__(256) void bias_init_kernel(
    const float* __restrict__ Param_b, const int* __restrict__ node_label,
    float* __restrict__ y, int n_nodes)
{
    int i = blockIdx.x * blockDim.x + threadIdx.x;
    if (i < n_nodes) y[i] = Param_b[node_label[i]];
}

__global__ __launch_bounds__(256) void edge_scatter_kernel(
    const float* __restrict__ x, const float* __restrict__ Param_W,
    const int* __restrict__ src, const int* __restrict__ dst,
    const int* __restrict__ widx, float* __restrict__ y, int n_edges)
{
    int i = (blockIdx.x * blockDim.x + threadIdx.x) * 4;
    if (i + 3 < n_edges) {
        int4 s = *reinterpret_cast<const int4*>(src + i);
        int4 d = *reinterpret_cast<const int4*>(dst + i);
        int4 w = *reinterpret_cast<const int4*>(widx + i);
        unsafeAtomicAdd(&y[d.x], Param_W[w.x] * x[s.x]);
        unsafeAtomicAdd(&y[d.y], Param_W[w.y] * x[s.y]);
        unsafeAtomicAdd(&y[d.z], Param_W[w.z] * x[s.z]);
        unsafeAtomicAdd(&y[d.w], Param_W[w.w] * x[s.w]);
    } else {
        for (; i < n_edges; ++i)
            unsafeAtomicAdd(&y[dst[i]], Param_W[widx[i]] * x[src[i]]);
    }
}

extern "C" void kernel_launch(void* const* d_in, const int* in_sizes, int n_in,
                              void* d_out, int out_size, void* d_ws, size_t ws_size,
                              hipStream_t stream)
{
    const float* x          = (const float*)d_in[0];
    const float* Param_W    = (const float*)d_in[1];
    const float* Param_b    = (const float*)d_in[2];
    const int*   src        = (const int*)d_in[3];
    const int*   dst        = (const int*)d_in[4];
    const int*   weight_idx = (const int*)d_in[5];
    const int*   node_label = (const int*)d_in[6];
    float* y = (float*)d_out;

    int n_nodes = in_sizes[0];
    int E       = in_sizes[3];

    size_t pairs_bytes    = (size_t)PARTS * CAP * sizeof(uint2);     // ~119.6 MB
    size_t partials_bytes = (size_t)NC * PADDED_N * sizeof(float);   // ~33.2 MB
    size_t need_new = 256 + pairs_bytes + partials_bytes;

    size_t fa_msg      = (size_t)E;
    size_t fa_partials = (size_t)F_NCHUNKS * F_PARTS * F_NPP;
    size_t need_fa     = (fa_msg + fa_partials) * sizeof(float);     // ~82.4 MB

    if (ws_size >= need_new) {
        int*   gcount   = (int*)d_ws;
        uint2* pairs    = (uint2*)((char*)d_ws + 256);
        float* partials = (float*)((char*)d_ws + 256 + pairs_bytes);

        zero_counts_kernel<<<1, 64, 0, stream>>>(gcount);

        int bin_blocks = (E + TILE - 1) / TILE;
        bin_kernel<<<bin_blocks, TPB_BIN, 0, stream>>>(
            x, Param_W, src, weight_idx, dst, pairs, gcount, E);

        scan2_kernel<<<PARTS * NC, TPB_SCAN, 0, stream>>>(pairs, gcount, partials);

        reduce2_kernel<<<(n_nodes + 255) / 256, 256, 0, stream>>>(
            partials, Param_b, node_label, y, n_nodes);
    } else if (ws_size >= need_fa) {
        float* msg      = (float*)d_ws;
        float* partials = msg + fa_msg;
        int tA = (E + 3) / 4;
        msg_kernel<<<(tA + 255) / 256, 256, 0, stream>>>(x, Param_W, src, weight_idx, msg, E);
        int chunk = (((E + F_NCHUNKS - 1) / F_NCHUNKS) + 3) & ~3;
        scan_kernel<<<F_PARTS * F_NCHUNKS, F_TPB, 0, stream>>>(dst, msg, partials, E, chunk);
        freduce_kernel<<<(n_nodes + 255) / 256, 256, 0, stream>>>(
            partials, Param_b, node_label, y, n_nodes);
    } else {
        bias_init_kernel<<<(n_nodes + 255) / 256, 256, 0, stream>>>(
            Param_b, node_label, y, n_nodes);
        int t = (E + 3) / 4;
        edge_scatter_kernel<<<(t + 255) / 256, 256, 0, stream>>>(
            x, Param_W, src, dst, weight_idx, y, E);
    }
}

// Round 5
// 371.564 us; speedup vs baseline: 2.0513x; 1.1050x over previous
//
#include <hip/hip_runtime.h>

// ---------------- Broadcast-5 constants ----------------
#define PARTS 5
#define NPP 40960                  // nodes per partition; 5*40960 = 204800 >= 200000
#define PADDED_N (PARTS * NPP)     // 204800
#define NCHUNKS 51                 // 5*51 = 255 blocks -> 1 block/CU, one residency round
#define TPB_SCAN 1024

// ---------------- Phase A: msg[e] = W[widx[e]] * x[src[e]] ----------------
__global__ __launch_bounds__(256) void msg_kernel(
    const float* __restrict__ x, const float* __restrict__ W,
    const int* __restrict__ src, const int* __restrict__ widx,
    float* __restrict__ msg, int E)
{
    int i = (blockIdx.x * 256 + threadIdx.x) * 4;
    if (i + 3 < E) {
        int4 s = *reinterpret_cast<const int4*>(src + i);
        int4 w = *reinterpret_cast<const int4*>(widx + i);
        float4 m;
        m.x = W[w.x] * x[s.x];
        m.y = W[w.y] * x[s.y];
        m.z = W[w.z] * x[s.z];
        m.w = W[w.w] * x[s.w];
        *reinterpret_cast<float4*>(msg + i) = m;
    } else {
        for (; i < E; ++i) msg[i] = W[widx[i]] * x[src[i]];
    }
}

// ---------------- Phase B: 5-partition broadcast scan, 160KB LDS ----------------
// block (c,p): scan edge chunk c, accumulate dsts in partition p into LDS,
// flush (non-atomic, coalesced) to partials[c][p*NPP ..].
// c-major block order: the 5 readers of chunk c are consecutive blockIdx ->
// temporally co-scheduled -> L2/LLC reuse of the (dst,msg) chunk.
__global__ __launch_bounds__(TPB_SCAN) void scan5_kernel(
    const int* __restrict__ dst, const float* __restrict__ msg,
    float* __restrict__ partials, int E, int chunk)
{
    extern __shared__ float acc[];   // NPP floats = 160 KB
    int p = blockIdx.x % PARTS;
    int c = blockIdx.x / PARTS;

    float4* a4 = reinterpret_cast<float4*>(acc);
    for (int i = threadIdx.x; i < NPP / 4; i += TPB_SCAN)
        a4[i] = make_float4(0.f, 0.f, 0.f, 0.f);
    __syncthreads();

    int lo = c * chunk;              // chunk is a multiple of 4
    int hi = min(E, lo + chunk);     // E is a multiple of 4
    int base = p * NPP;

    const int4*   d4 = reinterpret_cast<const int4*>(dst);
    const float4* m4 = reinterpret_cast<const float4*>(msg);
    for (int g = lo / 4 + threadIdx.x; g < hi / 4; g += TPB_SCAN) {
        int4   d = d4[g];
        float4 m = m4[g];
        unsigned r;
        r = (unsigned)(d.x - base); if (r < NPP) atomicAdd(&acc[r], m.x);
        r = (unsigned)(d.y - base); if (r < NPP) atomicAdd(&acc[r], m.y);
        r = (unsigned)(d.z - base); if (r < NPP) atomicAdd(&acc[r], m.z);
        r = (unsigned)(d.w - base); if (r < NPP) atomicAdd(&acc[r], m.w);
    }
    __syncthreads();

    float4* out4 = reinterpret_cast<float4*>(partials + (size_t)c * PADDED_N + base);
    for (int i = threadIdx.x; i < NPP / 4; i += TPB_SCAN)
        out4[i] = a4[i];
}

// ---------------- Phase C: reduce 51 slices + bias ----------------
__global__ __launch_bounds__(256) void reduce5_kernel(
    const float* __restrict__ partials, const float* __restrict__ bias,
    const int* __restrict__ label, float* __restrict__ y, int n)
{
    int i = blockIdx.x * 256 + threadIdx.x;
    if (i >= n) return;
    float s = bias[label[i]];
    #pragma unroll 1
    for (int c = 0; c < NCHUNKS; ++c)
        s += partials[(size_t)c * PADDED_N + i];
    y[i] = s;
}

// ---------------- Fallback (direct atomics) if ws too small ----------------
__global__ __launch_bounds__(256) void bias_init_kernel(
    const float* __restrict__ Param_b, const int* __restrict__ node_label,
    float* __restrict__ y, int n_nodes)
{
    int i = blockIdx.x * blockDim.x + threadIdx.x;
    if (i < n_nodes) y[i] = Param_b[node_label[i]];
}

__global__ __launch_bounds__(256) void edge_scatter_kernel(
    const float* __restrict__ x, const float* __restrict__ Param_W,
    const int* __restrict__ src, const int* __restrict__ dst,
    const int* __restrict__ widx, float* __restrict__ y, int n_edges)
{
    int i = (blockIdx.x * blockDim.x + threadIdx.x) * 4;
    if (i + 3 < n_edges) {
        int4 s = *reinterpret_cast<const int4*>(src + i);
        int4 d = *reinterpret_cast<const int4*>(dst + i);
        int4 w = *reinterpret_cast<const int4*>(widx + i);
        unsafeAtomicAdd(&y[d.x], Param_W[w.x] * x[s.x]);
        unsafeAtomicAdd(&y[d.y], Param_W[w.y] * x[s.y]);
        unsafeAtomicAdd(&y[d.z], Param_W[w.z] * x[s.z]);
        unsafeAtomicAdd(&y[d.w], Param_W[w.w] * x[s.w]);
    } else {
        for (; i < n_edges; ++i)
            unsafeAtomicAdd(&y[dst[i]], Param_W[widx[i]] * x[src[i]]);
    }
}

extern "C" void kernel_launch(void* const* d_in, const int* in_sizes, int n_in,
                              void* d_out, int out_size, void* d_ws, size_t ws_size,
                              hipStream_t stream)
{
    const float* x          = (const float*)d_in[0];
    const float* Param_W    = (const float*)d_in[1];
    const float* Param_b    = (const float*)d_in[2];
    const int*   src        = (const int*)d_in[3];
    const int*   dst        = (const int*)d_in[4];
    const int*   weight_idx = (const int*)d_in[5];
    const int*   node_label = (const int*)d_in[6];
    float* y = (float*)d_out;

    int n_nodes = in_sizes[0];
    int E       = in_sizes[3];

    size_t msg_elems      = (size_t)E;                         // 51.2 MB
    size_t partials_elems = (size_t)NCHUNKS * PADDED_N;        // 41.8 MB
    size_t need_bytes     = (msg_elems + partials_elems) * sizeof(float);

    if (ws_size >= need_bytes) {
        float* msg      = (float*)d_ws;
        float* partials = msg + msg_elems;

        // Phase A
        int tA = (E + 3) / 4;
        msg_kernel<<<(tA + 255) / 256, 256, 0, stream>>>(x, Param_W, src, weight_idx, msg, E);

        // Phase B: 160 KB dynamic LDS per block, 1 block/CU
        int chunk = (((E + NCHUNKS - 1) / NCHUNKS) + 3) & ~3;  // mult of 4
        scan5_kernel<<<PARTS * NCHUNKS, TPB_SCAN, NPP * sizeof(float), stream>>>(
            dst, msg, partials, E, chunk);

        // Phase C
        reduce5_kernel<<<(n_nodes + 255) / 256, 256, 0, stream>>>(
            partials, Param_b, node_label, y, n_nodes);
    } else {
        bias_init_kernel<<<(n_nodes + 255) / 256, 256, 0, stream>>>(
            Param_b, node_label, y, n_nodes);
        int t = (E + 3) / 4;
        edge_scatter_kernel<<<(t + 255) / 256, 256, 0, stream>>>(
            x, Param_W, src, dst, weight_idx, y, E);
    }
}

// Round 6
// 357.846 us; speedup vs baseline: 2.1299x; 1.0383x over previous
//
#include <hip/hip_runtime.h>

// ---------------- Broadcast-5 constants ----------------
#define PARTS 5
#define NPP 40960                  // nodes per partition; 5*40960 = 204800 >= 200000
#define PADDED_N (PARTS * NPP)     // 204800
#define NCHUNKS 51                 // 5*51 = 255 blocks -> 1 block/CU
#define TPB_SCAN 1024

typedef int   vint4   __attribute__((ext_vector_type(4)));
typedef float vfloat4 __attribute__((ext_vector_type(4)));

// ---------------- Phase A: msg[e] = W[widx[e]] * x[src[e]] ----------------
// Streams (src, widx, msg) are non-temporal so W (4MB) + x (800KB) stay
// L2-resident for the 25.6M random gathers. 8 edges/thread for MLP.
__global__ __launch_bounds__(256) void msg_kernel(
    const float* __restrict__ x, const float* __restrict__ W,
    const int* __restrict__ src, const int* __restrict__ widx,
    float* __restrict__ msg, int E)
{
    int i = (blockIdx.x * 256 + threadIdx.x) * 8;
    if (i + 7 < E) {
        vint4 s0 = __builtin_nontemporal_load(reinterpret_cast<const vint4*>(src + i));
        vint4 s1 = __builtin_nontemporal_load(reinterpret_cast<const vint4*>(src + i + 4));
        vint4 w0 = __builtin_nontemporal_load(reinterpret_cast<const vint4*>(widx + i));
        vint4 w1 = __builtin_nontemporal_load(reinterpret_cast<const vint4*>(widx + i + 4));

        // issue all 16 gathers, then combine
        float a0 = W[w0.x], a1 = W[w0.y], a2 = W[w0.z], a3 = W[w0.w];
        float a4 = W[w1.x], a5 = W[w1.y], a6 = W[w1.z], a7 = W[w1.w];
        float b0 = x[s0.x], b1 = x[s0.y], b2 = x[s0.z], b3 = x[s0.w];
        float b4 = x[s1.x], b5 = x[s1.y], b6 = x[s1.z], b7 = x[s1.w];

        vfloat4 m0, m1;
        m0.x = a0 * b0; m0.y = a1 * b1; m0.z = a2 * b2; m0.w = a3 * b3;
        m1.x = a4 * b4; m1.y = a5 * b5; m1.z = a6 * b6; m1.w = a7 * b7;
        __builtin_nontemporal_store(m0, reinterpret_cast<vfloat4*>(msg + i));
        __builtin_nontemporal_store(m1, reinterpret_cast<vfloat4*>(msg + i + 4));
    } else {
        for (; i < E; ++i) msg[i] = W[widx[i]] * x[src[i]];
    }
}

// ---------------- Phase B: 5-partition broadcast scan, 160KB LDS ----------------
__global__ __launch_bounds__(TPB_SCAN) void scan5_kernel(
    const int* __restrict__ dst, const float* __restrict__ msg,
    float* __restrict__ partials, int E, int chunk)
{
    extern __shared__ float acc[];   // NPP floats = 160 KB
    int p = blockIdx.x % PARTS;
    int c = blockIdx.x / PARTS;

    float4* a4 = reinterpret_cast<float4*>(acc);
    for (int i = threadIdx.x; i < NPP / 4; i += TPB_SCAN)
        a4[i] = make_float4(0.f, 0.f, 0.f, 0.f);
    __syncthreads();

    int lo = c * chunk;              // chunk is a multiple of 4
    int hi = min(E, lo + chunk);     // E is a multiple of 4
    int base = p * NPP;

    const int4*   d4 = reinterpret_cast<const int4*>(dst);
    const float4* m4 = reinterpret_cast<const float4*>(msg);
    for (int g = lo / 4 + threadIdx.x; g < hi / 4; g += TPB_SCAN) {
        int4   d = d4[g];
        float4 m = m4[g];
        unsigned r;
        r = (unsigned)(d.x - base); if (r < NPP) atomicAdd(&acc[r], m.x);
        r = (unsigned)(d.y - base); if (r < NPP) atomicAdd(&acc[r], m.y);
        r = (unsigned)(d.z - base); if (r < NPP) atomicAdd(&acc[r], m.z);
        r = (unsigned)(d.w - base); if (r < NPP) atomicAdd(&acc[r], m.w);
    }
    __syncthreads();

    vfloat4* out4 = reinterpret_cast<vfloat4*>(partials + (size_t)c * PADDED_N + base);
    const vfloat4* av4 = reinterpret_cast<const vfloat4*>(acc);
    for (int i = threadIdx.x; i < NPP / 4; i += TPB_SCAN)
        __builtin_nontemporal_store(av4[i], out4 + i);
}

// ---------------- Phase C: reduce 51 slices + bias ----------------
__global__ __launch_bounds__(256) void reduce5_kernel(
    const float* __restrict__ partials, const float* __restrict__ bias,
    const int* __restrict__ label, float* __restrict__ y, int n)
{
    int i = blockIdx.x * 256 + threadIdx.x;
    if (i >= n) return;
    float s0 = bias[label[i]];
    float s1 = 0.f, s2 = 0.f, s3 = 0.f;
    const float* p = partials + i;
    #pragma unroll 1
    for (int c = 0; c + 3 < NCHUNKS; c += 4) {
        s0 += __builtin_nontemporal_load(p + (size_t)(c + 0) * PADDED_N);
        s1 += __builtin_nontemporal_load(p + (size_t)(c + 1) * PADDED_N);
        s2 += __builtin_nontemporal_load(p + (size_t)(c + 2) * PADDED_N);
        s3 += __builtin_nontemporal_load(p + (size_t)(c + 3) * PADDED_N);
    }
    // NCHUNKS = 51 = 48 + 3
    s0 += __builtin_nontemporal_load(p + (size_t)48 * PADDED_N);
    s1 += __builtin_nontemporal_load(p + (size_t)49 * PADDED_N);
    s2 += __builtin_nontemporal_load(p + (size_t)50 * PADDED_N);
    y[i] = (s0 + s1) + (s2 + s3);
}

// ---------------- Fallback (direct atomics) if ws too small ----------------
__global__ __launch_bounds__(256) void bias_init_kernel(
    const float* __restrict__ Param_b, const int* __restrict__ node_label,
    float* __restrict__ y, int n_nodes)
{
    int i = blockIdx.x * blockDim.x + threadIdx.x;
    if (i < n_nodes) y[i] = Param_b[node_label[i]];
}

__global__ __launch_bounds__(256) void edge_scatter_kernel(
    const float* __restrict__ x, const float* __restrict__ Param_W,
    const int* __restrict__ src, const int* __restrict__ dst,
    const int* __restrict__ widx, float* __restrict__ y, int n_edges)
{
    int i = (blockIdx.x * blockDim.x + threadIdx.x) * 4;
    if (i + 3 < n_edges) {
        int4 s = *reinterpret_cast<const int4*>(src + i);
        int4 d = *reinterpret_cast<const int4*>(dst + i);
        int4 w = *reinterpret_cast<const int4*>(widx + i);
        unsafeAtomicAdd(&y[d.x], Param_W[w.x] * x[s.x]);
        unsafeAtomicAdd(&y[d.y], Param_W[w.y] * x[s.y]);
        unsafeAtomicAdd(&y[d.z], Param_W[w.z] * x[s.z]);
        unsafeAtomicAdd(&y[d.w], Param_W[w.w] * x[s.w]);
    } else {
        for (; i < n_edges; ++i)
            unsafeAtomicAdd(&y[dst[i]], Param_W[widx[i]] * x[src[i]]);
    }
}

extern "C" void kernel_launch(void* const* d_in, const int* in_sizes, int n_in,
                              void* d_out, int out_size, void* d_ws, size_t ws_size,
                              hipStream_t stream)
{
    const float* x          = (const float*)d_in[0];
    const float* Param_W    = (const float*)d_in[1];
    const float* Param_b    = (const float*)d_in[2];
    const int*   src        = (const int*)d_in[3];
    const int*   dst        = (const int*)d_in[4];
    const int*   weight_idx = (const int*)d_in[5];
    const int*   node_label = (const int*)d_in[6];
    float* y = (float*)d_out;

    int n_nodes = in_sizes[0];
    int E       = in_sizes[3];

    size_t msg_elems      = (size_t)E;                         // 51.2 MB
    size_t partials_elems = (size_t)NCHUNKS * PADDED_N;        // 41.8 MB
    size_t need_bytes     = (msg_elems + partials_elems) * sizeof(float);

    if (ws_size >= need_bytes) {
        float* msg      = (float*)d_ws;
        float* partials = msg + msg_elems;

        // Phase A: 8 edges/thread
        int tA = (E + 7) / 8;
        msg_kernel<<<(tA + 255) / 256, 256, 0, stream>>>(x, Param_W, src, weight_idx, msg, E);

        // Phase B: 160 KB dynamic LDS per block, 1 block/CU
        int chunk = (((E + NCHUNKS - 1) / NCHUNKS) + 3) & ~3;  // mult of 4
        scan5_kernel<<<PARTS * NCHUNKS, TPB_SCAN, NPP * sizeof(float), stream>>>(
            dst, msg, partials, E, chunk);

        // Phase C
        reduce5_kernel<<<(n_nodes + 255) / 256, 256, 0, stream>>>(
            partials, Param_b, node_label, y, n_nodes);
    } else {
        bias_init_kernel<<<(n_nodes + 255) / 256, 256, 0, stream>>>(
            Param_b, node_label, y, n_nodes);
        int t = (E + 3) / 4;
        edge_scatter_kernel<<<(t + 255) / 256, 256, 0, stream>>>(
            x, Param_W, src, dst, weight_idx, y, E);
    }
}